// Round 7
// baseline (112.318 us; speedup 1.0000x reference)
//
#include <hip/hip_runtime.h>

#define E_ 32640
#define PLANE_B 131072ull                       // bytes per (b,e) dense plane: 256*256*2
#define AG_BYTES (256ull * 3ull * PLANE_B)      // 100,663,296
#define WS_NEED (AG_BYTES + 512ull * 64ull * 4ull)

typedef __bf16 bf16x8 __attribute__((ext_vector_type(8)));
typedef float f32x4 __attribute__((ext_vector_type(4)));

__device__ __forceinline__ unsigned short cvt1(float f) {
  return __builtin_bit_cast(unsigned short, (__bf16)f);
}

// Swizzled LDS helpers: row-major bf16, byte ^= (row&7)<<4
__device__ __forceinline__ bf16x8 ldfrag(const unsigned short* base, int row, int kbyte, int rowbytes) {
  int byte = (row * rowbytes + kbyte) ^ ((row & 7) << 4);
  return *reinterpret_cast<const bf16x8*>(reinterpret_cast<const char*>(base) + byte);
}
__device__ __forceinline__ void st2(unsigned short* base, int row, int colbyte, int rowbytes, unsigned short v) {
  int byte = (row * rowbytes + colbyte) ^ ((row & 7) << 4);
  *reinterpret_cast<unsigned short*>(reinterpret_cast<char*>(base) + byte) = v;
}
__device__ __forceinline__ bf16x8 pack8(float4 lo, float4 hi) {
  bf16x8 r;
  r[0] = (__bf16)lo.x; r[1] = (__bf16)lo.y; r[2] = (__bf16)lo.z; r[3] = (__bf16)lo.w;
  r[4] = (__bf16)hi.x; r[5] = (__bf16)hi.y; r[6] = (__bf16)hi.z; r[7] = (__bf16)hi.w;
  return r;
}
__device__ __forceinline__ int ubase(int i) { return (i * (511 - i)) >> 1; }
__device__ __forceinline__ void decode_g(int g, int& gi, int& j) {
  float disc = (float)(261121 - 8 * g);
  int t = (int)((511.0f - sqrtf(disc)) * 0.5f);
  while (t * (511 - t) > 2 * g) --t;
  while ((t + 1) * (510 - t) <= 2 * g) ++t;
  gi = t;
  j = g - ((t * (511 - t)) >> 1) + t + 1;
}

// 32-row 3-plane store (planes +16384/+32768 B)
__device__ __forceinline__ void stA3_32(unsigned short* sA0, int lr, int cb, float4 v) {
  int byte = (lr * 512 + cb) ^ ((lr & 7) << 4);
  char* p = reinterpret_cast<char*>(sA0) + byte;
  *reinterpret_cast<unsigned short*>(p)         = cvt1(v.y);
  *reinterpret_cast<unsigned short*>(p + 16384) = cvt1(v.z);
  *reinterpret_cast<unsigned short*>(p + 32768) = cvt1(v.w);
}
// 16-row 3-plane store (planes +8192/+16384 B) — fallback path
__device__ __forceinline__ void stA3_16(unsigned short* sA0, int lr, int cb, float4 v) {
  int byte = (lr * 512 + cb) ^ ((lr & 7) << 4);
  char* p = reinterpret_cast<char*>(sA0) + byte;
  *reinterpret_cast<unsigned short*>(p)         = cvt1(v.y);
  *reinterpret_cast<unsigned short*>(p + 8192)  = cvt1(v.z);
  *reinterpret_cast<unsigned short*>(p + 16384) = cvt1(v.w);
}

#define WAITVM0 asm volatile("s_waitcnt vmcnt(0)" ::: "memory")

__device__ __forceinline__ void gld_lds16(const void* g, void* l) {
  __builtin_amdgcn_global_load_lds(
      (const __attribute__((address_space(1))) unsigned int*)g,
      (__attribute__((address_space(3))) unsigned int*)l, 16, 0, 0);
}
// One 16 KB tile: 8 waves x 2 passes x (64 lanes x 16 B)
__device__ __forceinline__ void dma_tile(const char* g, unsigned short* lbuf, int w, int l) {
  char* lb = reinterpret_cast<char*>(lbuf);
  #pragma unroll
  for (int p = 0; p < 2; ++p) {
    int seg = (w * 2 + p) * 1024;
    gld_lds16(g + seg + l * 16, lb + seg);
  }
}

// ================= Kernel 1: densify (b, 32-row stripe) =================
__global__ __launch_bounds__(512) void densify_kernel(
    const float* __restrict__ se_g, char* __restrict__ Ag)
{
  __shared__ __align__(16) unsigned short sA[3 * 32 * 256];  // 48 KB
  const int tid = threadIdx.x;
  const int i = blockIdx.x;
  const int batch  = (i & 7) * 32 + ((i >> 3) & 31);   // same-batch stripes share XCD
  const int r0     = (i >> 8) * 32;
  const float4* seB = reinterpret_cast<const float4*>(se_g) + (size_t)batch * E_;

  // (a) upper triangle: contiguous span, depth-2 pipelined
  {
    const int s0 = ubase(r0);
    const int S  = ubase(r0 + 32) - s0;
    int t = tid;
    float4 p0 = {}, p1 = {};
    if (t < S)       p0 = seB[s0 + t];
    if (t + 512 < S) p1 = seB[s0 + t + 512];
    for (; t < S; t += 512) {
      float4 v = p0; p0 = p1;
      if (t + 1024 < S) p1 = seB[s0 + t + 1024];
      int gi, j; decode_g(s0 + t, gi, j);
      stA3_32(sA, gi - r0, j * 2, v);
    }
  }
  // (b) lower triangle via column strips, x4 batched
  {
    const int sub = tid >> 5, l32 = tid & 31;
    const int K = (r0 + 31 + 15) >> 4;
    for (int k0 = 0; k0 < K; k0 += 4) {
      float4 v[4]; int lr[4], cb[4]; bool ok[4];
      #pragma unroll
      for (int kk = 0; kk < 4; ++kk) {
        int j  = sub + ((k0 + kk) << 4);
        int i0 = (j + 1 > r0) ? (j + 1) : r0;
        int cnt = r0 + 32 - i0;
        int ii = i0 + l32;
        bool val = (j < r0 + 31) && (l32 < cnt);
        int u = j * 255 - ((j * (j - 1)) >> 1) + (ii - j - 1);
        ok[kk] = val; lr[kk] = ii - r0; cb[kk] = j * 2;
        v[kk] = seB[val ? u : 0];
      }
      #pragma unroll
      for (int kk = 0; kk < 4; ++kk)
        if (ok[kk]) stA3_32(sA, lr[kk], cb[kk], v[kk]);
    }
  }
  if (tid < 32) {  // diagonal = 0
    int byte = (tid * 512 + (r0 + tid) * 2) ^ ((tid & 7) << 4);
    char* p = reinterpret_cast<char*>(sA) + byte;
    *reinterpret_cast<unsigned short*>(p)         = 0;
    *reinterpret_cast<unsigned short*>(p + 16384) = 0;
    *reinterpret_cast<unsigned short*>(p + 32768) = 0;
  }
  __syncthreads();

  // dump swizzled LDS linearly -> pre-swizzled dense global tiles
  for (int t = tid; t < 3072; t += 512) {
    int e = t >> 10;
    int off = (t & 1023) << 4;
    uint4 v = *reinterpret_cast<const uint4*>(reinterpret_cast<const char*>(sA) + e * 16384 + off);
    *reinterpret_cast<uint4*>(Ag + ((size_t)(batch * 3 + e)) * PLANE_B + (size_t)r0 * 512 + off) = v;
  }
}

// ================= Kernel 2: DMA-staged GEMM chain (b, half) =================
__global__ __launch_bounds__(512, 2) void gemm_kernel(
    const char* __restrict__ Ag,
    const float* __restrict__ w1,  const float* __restrict__ b1,
    const float* __restrict__ w2,  const float* __restrict__ b2,
    const float* __restrict__ wo1, const float* __restrict__ bo1,
    const float* __restrict__ wo2, const float* __restrict__ bo2,
    float* __restrict__ pw)
{
  __shared__ __align__(16) unsigned short sA2[2 * 32 * 256];  // 2 x 16 KB DMA bufs
  __shared__ __align__(16) unsigned short sH3[3 * 32 * 128];  // 24 KB; X/P overlay on plane 0
  __shared__ float sAccW[8][64];

  const int tid = threadIdx.x;
  const int i = blockIdx.x;
  const int batch = (i & 7) * 32 + ((i >> 3) & 31);
  const int half  = i >> 8;

  const int w   = tid >> 6;
  const int l   = tid & 63;
  const int l15 = l & 15;
  const int lk  = l >> 4;
  const int kb0 = lk * 16;
  const int c1 = w;        // GEMM1 col-tile (of 8)
  const int r2 = w >> 2;   // GEMM2/head row-tile (of 2)
  const int c2 = w & 3;    // GEMM2/head col-tile (of 4)

  reinterpret_cast<float*>(sAccW)[tid] = 0.f;

  // persistent weight fragments
  bf16x8 W1f[8];
  {
    const float* p = w1 + (c1 * 16 + l15) * 256 + lk * 8;
    #pragma unroll
    for (int ks = 0; ks < 8; ++ks)
      W1f[ks] = pack8(*reinterpret_cast<const float4*>(p + ks * 32),
                      *reinterpret_cast<const float4*>(p + ks * 32 + 4));
  }
  bf16x8 W2f[4];
  {
    const float* p = w2 + (c2 * 16 + l15) * 128 + lk * 8;
    #pragma unroll
    for (int ks = 0; ks < 4; ++ks)
      W2f[ks] = pack8(*reinterpret_cast<const float4*>(p + ks * 32),
                      *reinterpret_cast<const float4*>(p + ks * 32 + 4));
  }
  bf16x8 WO1f[2], WO2f[2];
  {
    const float* q1 = wo1 + (c2 * 16 + l15) * 64 + lk * 8;
    const float* q2 = wo2 + (c2 * 16 + l15) * 64 + lk * 8;
    #pragma unroll
    for (int ks = 0; ks < 2; ++ks) {
      WO1f[ks] = pack8(*reinterpret_cast<const float4*>(q1 + ks * 32),
                       *reinterpret_cast<const float4*>(q1 + ks * 32 + 4));
      WO2f[ks] = pack8(*reinterpret_cast<const float4*>(q2 + ks * 32),
                       *reinterpret_cast<const float4*>(q2 + ks * 32 + 4));
    }
  }
  const float b1v  = b1[c1 * 16 + l15];
  const float b2v  = b2[c2 * 16 + l15];
  const float bo1v = bo1[c2 * 16 + l15];
  const float bo2v = bo2[c2 * 16 + l15];

  const char* Abase = Ag + (size_t)batch * 3 * PLANE_B + (size_t)half * 128 * 512;
  unsigned short* sX = sH3;           // bytes [0,4096)
  unsigned short* sP = sH3 + 2048;    // bytes [4096,8192)

  // tile t (t=0..11): chunk c=t/3, e=t%3; 16 KB each
  #define TILE_SRC(t) (Abase + (size_t)((t) - ((t) / 3) * 3) * PLANE_B + (size_t)((t) / 3) * 32 * 512)

  dma_tile(TILE_SRC(0), sA2, w, l);   // prologue: tile 0 -> buf 0

  #pragma unroll 1
  for (int t = 0; t < 12; ++t) {
    WAITVM0;            // own DMA pieces of tile t landed
    __syncthreads();    // whole tile t resident; GEMM1_{t-1} done by all -> buf (t+1)&1 free
    if (t < 11) dma_tile(TILE_SRC(t + 1), sA2 + ((t + 1) & 1) * 8192, w, l);

    // GEMM1_t: H3[e] = relu(A_e @ W1^T + b1), e = t%3
    {
      const unsigned short* sAe = sA2 + (t & 1) * 8192;
      const int e = t - (t / 3) * 3;
      unsigned short* sHe = sH3 + e * 4096;
      f32x4 acc0 = {0, 0, 0, 0}, acc1 = {0, 0, 0, 0};
      #pragma unroll
      for (int ks = 0; ks < 8; ++ks) {
        int kb = ks * 64 + kb0;
        acc0 = __builtin_amdgcn_mfma_f32_16x16x32_bf16(ldfrag(sAe, l15,      kb, 512), W1f[ks], acc0, 0, 0, 0);
        acc1 = __builtin_amdgcn_mfma_f32_16x16x32_bf16(ldfrag(sAe, 16 + l15, kb, 512), W1f[ks], acc1, 0, 0, 0);
      }
      int cc = c1 * 16 + l15;
      #pragma unroll
      for (int r = 0; r < 4; ++r) {
        st2(sHe, lk * 4 + r,      cc * 2, 256, cvt1(fmaxf(acc0[r] + b1v, 0.f)));
        st2(sHe, 16 + lk * 4 + r, cc * 2, 256, cvt1(fmaxf(acc1[r] + b1v, 0.f)));
      }
    }

    if (t - (t / 3) * 3 == 2) {   // chunk tail: GEMM2 + head (DMA for next tile in flight)
      __syncthreads();   // H3 complete
      f32x4 outAcc = {0, 0, 0, 0};
      {
        int arow = r2 * 16 + l15;
        #pragma unroll
        for (int e = 0; e < 3; ++e) {
          f32x4 acc = {0, 0, 0, 0};
          const unsigned short* sHe = sH3 + e * 4096;
          #pragma unroll
          for (int ks = 0; ks < 4; ++ks)
            acc = __builtin_amdgcn_mfma_f32_16x16x32_bf16(
                ldfrag(sHe, arow, ks * 64 + kb0, 256), W2f[ks], acc, 0, 0, 0);
          float wte = 0.2f * (float)(e + 1);
          #pragma unroll
          for (int r = 0; r < 4; ++r)
            outAcc[r] += wte * fmaxf(acc[r] + b2v, 0.f);
        }
      }
      __syncthreads();   // all H3 reads done -> overlay X onto H3[0]
      #pragma unroll
      for (int r = 0; r < 4; ++r)
        st2(sX, r2 * 16 + lk * 4 + r, (c2 * 16 + l15) * 2, 128, cvt1(outAcc[r]));
      __syncthreads();   // X ready
      {
        f32x4 acc = {0, 0, 0, 0};
        int arow = r2 * 16 + l15;
        #pragma unroll
        for (int ks = 0; ks < 2; ++ks)
          acc = __builtin_amdgcn_mfma_f32_16x16x32_bf16(
              ldfrag(sX, arow, ks * 64 + kb0, 128), WO1f[ks], acc, 0, 0, 0);
        #pragma unroll
        for (int r = 0; r < 4; ++r)
          st2(sP, r2 * 16 + lk * 4 + r, (c2 * 16 + l15) * 2, 128, cvt1(fmaxf(acc[r] + bo1v, 0.f)));
      }
      __syncthreads();   // P ready
      {
        f32x4 acc = {0, 0, 0, 0};
        int arow = r2 * 16 + l15;
        #pragma unroll
        for (int ks = 0; ks < 2; ++ks)
          acc = __builtin_amdgcn_mfma_f32_16x16x32_bf16(
              ldfrag(sP, arow, ks * 64 + kb0, 128), WO2f[ks], acc, 0, 0, 0);
        float s = 0.f;
        #pragma unroll
        for (int r = 0; r < 4; ++r) s += fmaxf(acc[r] + bo2v, 0.f);
        s += __shfl_xor(s, 16);
        s += __shfl_xor(s, 32);
        if (lk == 0) sAccW[w][c2 * 16 + l15] += s;
      }
      // next iter's top barrier orders sP/sX reuse (H3[0] rewrite by GEMM1)
    }
  }
  #undef TILE_SRC
  __syncthreads();
  if (tid < 64) {
    float s = 0.f;
    #pragma unroll
    for (int ww = 0; ww < 8; ++ww) s += sAccW[ww][tid];
    pw[((size_t)batch * 2 + half) * 64 + tid] = s;
  }
}

// ================= finish: sum halves, mean, 64->2 =================
__global__ __launch_bounds__(512) void finish_kernel(
    const float* __restrict__ pw,
    const float* __restrict__ wo3, const float* __restrict__ bo3,
    float* __restrict__ out)
{
  int b = blockIdx.x * 8 + (threadIdx.x >> 6);
  int l = threadIdx.x & 63;
  float s = (pw[((size_t)b * 2 + 0) * 64 + l] + pw[((size_t)b * 2 + 1) * 64 + l]) * (1.0f / 256.0f);
  float v0 = s * wo3[l];
  float v1 = s * wo3[64 + l];
  #pragma unroll
  for (int off = 32; off > 0; off >>= 1) {
    v0 += __shfl_down(v0, off);
    v1 += __shfl_down(v1, off);
  }
  if (l == 0) {
    out[b * 2 + 0] = v0 + bo3[0];
    out[b * 2 + 1] = v1 + bo3[1];
  }
}

// ================= Fallback (round-6 fused kernel, needs only 128 KB ws) =================
__device__ __forceinline__ void fb_stage_lower(const float4* seB, unsigned short* sA,
                                               int r0, int glane, int ngroups) {
  const int sub = glane >> 4, l16 = glane & 15;
  const int nStrips = r0 + 15;
  for (int j0 = sub; j0 < nStrips; j0 += ngroups * 4) {
    float4 v[4]; int lr[4], cb[4]; bool ok[4];
    #pragma unroll
    for (int kk = 0; kk < 4; ++kk) {
      int j  = j0 + kk * ngroups;
      int i0 = (j + 1 > r0) ? (j + 1) : r0;
      int cnt = r0 + 16 - i0;
      int ii = i0 + l16;
      bool val = (j < nStrips) && (l16 < cnt);
      int u = j * 255 - ((j * (j - 1)) >> 1) + (ii - j - 1);
      ok[kk] = val; lr[kk] = ii - r0; cb[kk] = j * 2;
      v[kk] = seB[val ? u : 0];
    }
    #pragma unroll
    for (int kk = 0; kk < 4; ++kk)
      if (ok[kk]) stA3_16(sA, lr[kk], cb[kk], v[kk]);
  }
}
__device__ __forceinline__ void fb_stage_upper(const float4* seB, unsigned short* sA,
                                               int r0, int tid) {
  const int s0 = ubase(r0);
  const int S  = ubase(r0 + 16) - s0;
  int t = tid;
  float4 p0 = {}, p1 = {};
  if (t < S)       p0 = seB[s0 + t];
  if (t + 512 < S) p1 = seB[s0 + t + 512];
  for (; t < S; t += 512) {
    float4 v = p0; p0 = p1;
    if (t + 1024 < S) p1 = seB[s0 + t + 1024];
    int gi, j; decode_g(s0 + t, gi, j);
    stA3_16(sA, gi - r0, j * 2, v);
  }
}

__global__ __launch_bounds__(512, 2) void fb_kernel(
    const float* __restrict__ se_g,
    const float* __restrict__ w1,  const float* __restrict__ b1,
    const float* __restrict__ w2,  const float* __restrict__ b2,
    const float* __restrict__ wo1, const float* __restrict__ bo1,
    const float* __restrict__ wo2, const float* __restrict__ bo2,
    float* __restrict__ ws)
{
  __shared__ __align__(16) unsigned short sA[3 * 16 * 256];
  __shared__ __align__(16) unsigned short sH3[3 * 16 * 128];
  __shared__ __align__(16) unsigned short sXP[2 * 16 * 64];
  __shared__ float sAccC[64];

  const int tid = threadIdx.x;
  const int i   = blockIdx.x;
  const int half  = i >> 8;
  const int within = i & 255;
  const int batch = (within & 7) * 32 + (within >> 3);
  const int cbase = half * 8;

  const int w   = tid >> 6;
  const int l   = tid & 63;
  const int l15 = l & 15;
  const int lk  = l >> 4;
  const int kb0 = lk * 16;
  const int c1 = w;
  const int c2 = w & 3;
  const bool isHead = (w < 4);

  if (tid < 64) sAccC[tid] = 0.f;

  bf16x8 W1f[8];
  {
    const float* p = w1 + (c1 * 16 + l15) * 256 + lk * 8;
    #pragma unroll
    for (int ks = 0; ks < 8; ++ks)
      W1f[ks] = pack8(*reinterpret_cast<const float4*>(p + ks * 32),
                      *reinterpret_cast<const float4*>(p + ks * 32 + 4));
  }
  bf16x8 W2f[4];
  {
    const float* p = w2 + (c2 * 16 + l15) * 128 + lk * 8;
    #pragma unroll
    for (int ks = 0; ks < 4; ++ks)
      W2f[ks] = pack8(*reinterpret_cast<const float4*>(p + ks * 32),
                      *reinterpret_cast<const float4*>(p + ks * 32 + 4));
  }
  const float b1v  = b1[c1 * 16 + l15];
  const float b2v  = b2[c2 * 16 + l15];
  const float bo1v = bo1[c2 * 16 + l15];
  const float bo2v = bo2[c2 * 16 + l15];

  const float4* seB = reinterpret_cast<const float4*>(se_g) + (size_t)batch * E_;
  unsigned short* sX = sXP;
  unsigned short* sP = sXP + 16 * 64;

  {
    int r0 = cbase * 16;
    fb_stage_upper(seB, sA, r0, tid);
    fb_stage_lower(seB, sA, r0, tid, 32);
    if (tid < 16) {
      int byte = (tid * 512 + (r0 + tid) * 2) ^ ((tid & 7) << 4);
      char* p = reinterpret_cast<char*>(sA) + byte;
      *reinterpret_cast<unsigned short*>(p)         = 0;
      *reinterpret_cast<unsigned short*>(p + 8192)  = 0;
      *reinterpret_cast<unsigned short*>(p + 16384) = 0;
    }
  }
  __syncthreads();

  for (int cc = 0; cc < 8; ++cc) {
    const int r0 = (cbase + cc) * 16;
    const bool more = (cc < 7);
    const int nr0 = r0 + 16;

    float4 pf[8];
    int s0 = 0, S = 0;
    if (more) {
      s0 = ubase(nr0);
      S  = ubase(nr0 + 16) - s0;
      #pragma unroll
      for (int k = 0; k < 8; ++k) {
        int t = tid + k * 512;
        pf[k] = seB[s0 + (t < S ? t : 0)];
      }
    }
    {
      const int ccol = c1 * 16 + l15;
      #pragma unroll
      for (int e = 0; e < 3; ++e) {
        f32x4 acc = {0, 0, 0, 0};
        const unsigned short* sAe = sA + e * 4096;
        #pragma unroll
        for (int ks = 0; ks < 8; ++ks)
          acc = __builtin_amdgcn_mfma_f32_16x16x32_bf16(
              ldfrag(sAe, l15, ks * 64 + kb0, 512), W1f[ks], acc, 0, 0, 0);
        unsigned short* sHe = sH3 + e * 2048;
        #pragma unroll
        for (int r = 0; r < 4; ++r)
          st2(sHe, lk * 4 + r, ccol * 2, 256, cvt1(fmaxf(acc[r] + b1v, 0.f)));
      }
    }
    __syncthreads();

    if (more) {
      #pragma unroll
      for (int k = 0; k < 8; ++k) {
        int t = tid + k * 512;
        if (t < S) {
          int gi, j; decode_g(s0 + t, gi, j);
          stA3_16(sA, gi - nr0, j * 2, pf[k]);
        }
      }
      if (tid < 16) {
        int byte = (tid * 512 + (nr0 + tid) * 2) ^ ((tid & 7) << 4);
        char* p = reinterpret_cast<char*>(sA) + byte;
        *reinterpret_cast<unsigned short*>(p)         = 0;
        *reinterpret_cast<unsigned short*>(p + 8192)  = 0;
        *reinterpret_cast<unsigned short*>(p + 16384) = 0;
      }
    }
    bf16x8 WO1f[2], WO2f[2];
    if (isHead) {
      const float* q1 = wo1 + (c2 * 16 + l15) * 64 + lk * 8;
      const float* q2 = wo2 + (c2 * 16 + l15) * 64 + lk * 8;
      f32x4 outAcc = {0, 0, 0, 0};
      #pragma unroll
      for (int e = 0; e < 3; ++e) {
        f32x4 acc = {0, 0, 0, 0};
        const unsigned short* sHe = sH3 + e * 2048;
        #pragma unroll
        for (int ks = 0; ks < 4; ++ks)
          acc = __builtin_amdgcn_mfma_f32_16x16x32_bf16(
              ldfrag(sHe, l15, ks * 64 + kb0, 256), W2f[ks], acc, 0, 0, 0);
        float wte = 0.2f * (float)(e + 1);
        #pragma unroll
        for (int r = 0; r < 4; ++r)
          outAcc[r] += wte * fmaxf(acc[r] + b2v, 0.f);
      }
      WO1f[0] = pack8(*reinterpret_cast<const float4*>(q1), *reinterpret_cast<const float4*>(q1 + 4));
      WO1f[1] = pack8(*reinterpret_cast<const float4*>(q1 + 32), *reinterpret_cast<const float4*>(q1 + 36));
      WO2f[0] = pack8(*reinterpret_cast<const float4*>(q2), *reinterpret_cast<const float4*>(q2 + 4));
      WO2f[1] = pack8(*reinterpret_cast<const float4*>(q2 + 32), *reinterpret_cast<const float4*>(q2 + 36));
      #pragma unroll
      for (int r = 0; r < 4; ++r)
        st2(sX, lk * 4 + r, (c2 * 16 + l15) * 2, 128, cvt1(outAcc[r]));
    } else if (more) {
      fb_stage_lower(seB, sA, nr0, tid - 256, 16);
    }
    __syncthreads();

    if (isHead) {
      f32x4 acc = {0, 0, 0, 0};
      #pragma unroll
      for (int ks = 0; ks < 2; ++ks)
        acc = __builtin_amdgcn_mfma_f32_16x16x32_bf16(
            ldfrag(sX, l15, ks * 64 + kb0, 128), WO1f[ks], acc, 0, 0, 0);
      #pragma unroll
      for (int r = 0; r < 4; ++r)
        st2(sP, lk * 4 + r, (c2 * 16 + l15) * 2, 128, cvt1(fmaxf(acc[r] + bo1v, 0.f)));
    }
    __syncthreads();
    if (isHead) {
      f32x4 acc = {0, 0, 0, 0};
      #pragma unroll
      for (int ks = 0; ks < 2; ++ks)
        acc = __builtin_amdgcn_mfma_f32_16x16x32_bf16(
            ldfrag(sP, l15, ks * 64 + kb0, 128), WO2f[ks], acc, 0, 0, 0);
      float s = 0.f;
      #pragma unroll
      for (int r = 0; r < 4; ++r) s += fmaxf(acc[r] + bo2v, 0.f);
      s += __shfl_xor(s, 16);
      s += __shfl_xor(s, 32);
      if (lk == 0) sAccC[c2 * 16 + l15] += s;
    }
    __syncthreads();
  }
  if (tid < 64) ws[((size_t)batch * 2 + half) * 64 + tid] = sAccC[tid];
}

extern "C" void kernel_launch(void* const* d_in, const int* in_sizes, int n_in,
                              void* d_out, int out_size, void* d_ws, size_t ws_size,
                              hipStream_t stream) {
  (void)in_sizes; (void)n_in; (void)out_size;
  const float* se  = (const float*)d_in[1];   // d_in[0] = `inputs` — shape-only, never read
  const float* w1  = (const float*)d_in[2];
  const float* b1  = (const float*)d_in[3];
  const float* w2  = (const float*)d_in[4];
  const float* b2  = (const float*)d_in[5];
  const float* wo1 = (const float*)d_in[6];
  const float* bo1 = (const float*)d_in[7];
  const float* wo2 = (const float*)d_in[8];
  const float* bo2 = (const float*)d_in[9];
  const float* wo3 = (const float*)d_in[10];
  const float* bo3 = (const float*)d_in[11];

  if (ws_size >= WS_NEED) {
    char*  Ag = (char*)d_ws;
    float* pw = (float*)((char*)d_ws + AG_BYTES);
    densify_kernel<<<dim3(2048), dim3(512), 0, stream>>>(se, Ag);
    gemm_kernel<<<dim3(512), dim3(512), 0, stream>>>(
        Ag, w1, b1, w2, b2, wo1, bo1, wo2, bo2, pw);
    finish_kernel<<<dim3(32), dim3(512), 0, stream>>>(pw, wo3, bo3, (float*)d_out);
  } else {
    float* pw = (float*)d_ws;   // 512*64 floats = 128 KB
    fb_kernel<<<dim3(512), dim3(512), 0, stream>>>(
        se, w1, b1, w2, b2, wo1, bo1, wo2, bo2, pw);
    finish_kernel<<<dim3(32), dim3(512), 0, stream>>>(pw, wo3, bo3, (float*)d_out);
  }
}

// Round 8
// 111.602 us; speedup vs baseline: 1.0064x; 1.0064x over previous
//
#include <hip/hip_runtime.h>

#define E_ 32640

typedef __bf16 bf16x8 __attribute__((ext_vector_type(8)));
typedef float f32x4 __attribute__((ext_vector_type(4)));

__device__ __forceinline__ unsigned short cvt1(float f) {
  return __builtin_bit_cast(unsigned short, (__bf16)f);
}

// Swizzled LDS helpers: row-major bf16, byte ^= (row&7)<<4
__device__ __forceinline__ bf16x8 ldfrag(const unsigned short* base, int row, int kbyte, int rowbytes) {
  int byte = (row * rowbytes + kbyte) ^ ((row & 7) << 4);
  return *reinterpret_cast<const bf16x8*>(reinterpret_cast<const char*>(base) + byte);
}
__device__ __forceinline__ void st2(unsigned short* base, int row, int colbyte, int rowbytes, unsigned short v) {
  int byte = (row * rowbytes + colbyte) ^ ((row & 7) << 4);
  *reinterpret_cast<unsigned short*>(reinterpret_cast<char*>(base) + byte) = v;
}
__device__ __forceinline__ bf16x8 pack8(float4 lo, float4 hi) {
  bf16x8 r;
  r[0] = (__bf16)lo.x; r[1] = (__bf16)lo.y; r[2] = (__bf16)lo.z; r[3] = (__bf16)lo.w;
  r[4] = (__bf16)hi.x; r[5] = (__bf16)hi.y; r[6] = (__bf16)hi.z; r[7] = (__bf16)hi.w;
  return r;
}
__device__ __forceinline__ int ubase(int i) { return (i * (511 - i)) >> 1; }
__device__ __forceinline__ void decode_g(int g, int& gi, int& j) {
  float disc = (float)(261121 - 8 * g);
  int t = (int)((511.0f - sqrtf(disc)) * 0.5f);
  while (t * (511 - t) > 2 * g) --t;
  while ((t + 1) * (510 - t) <= 2 * g) ++t;
  gi = t;
  j = g - ((t * (511 - t)) >> 1) + t + 1;
}
// 16-row 3-plane store (planes +8192/+16384 B)
__device__ __forceinline__ void stA3(unsigned short* sA0, int lr, int cb, float4 v) {
  int byte = (lr * 512 + cb) ^ ((lr & 7) << 4);
  char* p = reinterpret_cast<char*>(sA0) + byte;
  *reinterpret_cast<unsigned short*>(p)         = cvt1(v.y);
  *reinterpret_cast<unsigned short*>(p + 8192)  = cvt1(v.z);
  *reinterpret_cast<unsigned short*>(p + 16384) = cvt1(v.w);
}

// ======== stage1: scatter 16-row stripe + GEMM1 + GEMM2 -> M[b][256][64] f32 ========
// 4096 blocks = (batch, stripe 0..15), 512 threads.
__global__ __launch_bounds__(512, 4) void stage1_kernel(
    const float* __restrict__ se_g,
    const float* __restrict__ w1,  const float* __restrict__ b1,
    const float* __restrict__ w2,  const float* __restrict__ b2,
    float* __restrict__ Mg)
{
  __shared__ __align__(16) unsigned short sA[3 * 16 * 256];   // 24 KB, rowbytes 512
  __shared__ __align__(16) unsigned short sH3[3 * 16 * 128];  // 12 KB, rowbytes 256

  const int tid = threadIdx.x;
  const int i   = blockIdx.x;
  const int batch  = (i & 7) * 32 + ((i >> 3) & 31);   // XCD-grouped batches
  const int stripe = i >> 8;                            // 0..15
  const int r0     = stripe * 16;

  const int w   = tid >> 6;   // wave 0..7
  const int l   = tid & 63;
  const int l15 = l & 15;
  const int lk  = l >> 4;
  const int kb0 = lk * 16;

  const float4* seB = reinterpret_cast<const float4*>(se_g) + (size_t)batch * E_;

  // ---- issue ALL independent loads up front ----
  // lower: rows j < r0, 2 threads per row, 8 contiguous edges each (cols r0+8h..+8)
  float4 lv[8];
  const bool hasL = tid < 2 * r0;
  const int  j_l  = tid >> 1;
  const int  h_l  = tid & 1;
  if (hasL) {
    int u = j_l * 255 - ((j_l * (j_l - 1)) >> 1) + (r0 - j_l - 1) + 8 * h_l;
    #pragma unroll
    for (int k = 0; k < 8; ++k) lv[k] = seB[u + k];
  }
  // upper: contiguous span of rows [r0, r0+16), S <= 3960 <= 8*512
  const int s0 = ubase(r0);
  const int S  = ubase(r0 + 16) - s0;
  float4 pf[8];
  #pragma unroll
  for (int k = 0; k < 8; ++k) {
    int t = tid + k * 512;
    pf[k] = seB[s0 + (t < S ? t : 0)];
  }

  // ---- store lower (no decode needed) ----
  if (hasL) {
    #pragma unroll
    for (int k = 0; k < 8; ++k)
      stA3(sA, 8 * h_l + k, j_l * 2, lv[k]);   // tile row = i-r0, col = j
  }
  // ---- decode + store upper (+ in-stripe mirror) ----
  #pragma unroll
  for (int k = 0; k < 8; ++k) {
    int t = tid + k * 512;
    if (t < S) {
      int gi, j; decode_g(s0 + t, gi, j);
      stA3(sA, gi - r0, j * 2, pf[k]);
      if (j < r0 + 16) stA3(sA, j - r0, gi * 2, pf[k]);  // mirror inside stripe
    }
  }
  // diagonal = 0
  if (tid < 16) {
    int byte = (tid * 512 + (r0 + tid) * 2) ^ ((tid & 7) << 4);
    char* p = reinterpret_cast<char*>(sA) + byte;
    *reinterpret_cast<unsigned short*>(p)         = 0;
    *reinterpret_cast<unsigned short*>(p + 8192)  = 0;
    *reinterpret_cast<unsigned short*>(p + 16384) = 0;
  }
  __syncthreads();   // A staged

  // ---- weights AFTER staging (keeps pf/lv register pressure isolated) ----
  bf16x8 W1f[8];
  {
    const float* p = w1 + (w * 16 + l15) * 256 + lk * 8;   // col-tile = wave
    #pragma unroll
    for (int ks = 0; ks < 8; ++ks)
      W1f[ks] = pack8(*reinterpret_cast<const float4*>(p + ks * 32),
                      *reinterpret_cast<const float4*>(p + ks * 32 + 4));
  }
  const float b1v = b1[w * 16 + l15];

  // ---- GEMM1: H3[e][16][128] = relu(A_e @ W1^T + b1) ----
  #pragma unroll
  for (int e = 0; e < 3; ++e) {
    f32x4 acc = {0, 0, 0, 0};
    const unsigned short* sAe = sA + e * 4096;   // 8192 B per plane
    #pragma unroll
    for (int ks = 0; ks < 8; ++ks)
      acc = __builtin_amdgcn_mfma_f32_16x16x32_bf16(
          ldfrag(sAe, l15, ks * 64 + kb0, 512), W1f[ks], acc, 0, 0, 0);
    unsigned short* sHe = sH3 + e * 2048;
    int cc = w * 16 + l15;
    #pragma unroll
    for (int r = 0; r < 4; ++r)
      st2(sHe, lk * 4 + r, cc * 2, 256, cvt1(fmaxf(acc[r] + b1v, 0.f)));
  }
  __syncthreads();   // H ready

  // ---- GEMM2 (waves 0-3): M[16][64] = sum_e wte*relu(H_e @ W2^T + b2) -> global f32 ----
  if (w < 4) {
    bf16x8 W2f[4];
    {
      const float* p = w2 + (w * 16 + l15) * 128 + lk * 8;
      #pragma unroll
      for (int ks = 0; ks < 4; ++ks)
        W2f[ks] = pack8(*reinterpret_cast<const float4*>(p + ks * 32),
                        *reinterpret_cast<const float4*>(p + ks * 32 + 4));
    }
    const float b2v = b2[w * 16 + l15];
    f32x4 osum = {0, 0, 0, 0};
    #pragma unroll
    for (int e = 0; e < 3; ++e) {
      f32x4 acc = {0, 0, 0, 0};
      const unsigned short* sHe = sH3 + e * 2048;
      #pragma unroll
      for (int ks = 0; ks < 4; ++ks)
        acc = __builtin_amdgcn_mfma_f32_16x16x32_bf16(
            ldfrag(sHe, l15, ks * 64 + kb0, 256), W2f[ks], acc, 0, 0, 0);
      float wte = 0.2f * (float)(e + 1);
      #pragma unroll
      for (int r = 0; r < 4; ++r)
        osum[r] += wte * fmaxf(acc[r] + b2v, 0.f);
    }
    #pragma unroll
    for (int r = 0; r < 4; ++r)
      Mg[((size_t)batch * 256 + r0 + lk * 4 + r) * 64 + w * 16 + l15] = osum[r];
  }
}

// ======== head: per batch, M[256][64] -> P1 -> P2 -> rowsum -> mean -> 64->2 ========
__global__ __launch_bounds__(512) void head_kernel(
    const float* __restrict__ Mg,
    const float* __restrict__ wo1, const float* __restrict__ bo1,
    const float* __restrict__ wo2, const float* __restrict__ bo2,
    const float* __restrict__ wo3, const float* __restrict__ bo3,
    float* __restrict__ out)
{
  __shared__ __align__(16) unsigned short sX[32 * 64];  // 4 KB, rowbytes 128
  __shared__ __align__(16) unsigned short sP[32 * 64];  // 4 KB
  __shared__ float sAccW[8][64];
  __shared__ float sMean[64];

  const int tid = threadIdx.x;
  const int b   = blockIdx.x;
  const int w   = tid >> 6;
  const int l   = tid & 63;
  const int l15 = l & 15;
  const int lk  = l >> 4;
  const int kb0 = lk * 16;
  const int r2  = w >> 2;   // rowtile of 32-row chunk
  const int c2  = w & 3;    // coltile

  reinterpret_cast<float*>(sAccW)[tid] = 0.f;  // wave-private rows -> no hazard

  bf16x8 WO1f[2], WO2f[2];
  {
    const float* q1 = wo1 + (c2 * 16 + l15) * 64 + lk * 8;
    const float* q2 = wo2 + (c2 * 16 + l15) * 64 + lk * 8;
    #pragma unroll
    for (int ks = 0; ks < 2; ++ks) {
      WO1f[ks] = pack8(*reinterpret_cast<const float4*>(q1 + ks * 32),
                       *reinterpret_cast<const float4*>(q1 + ks * 32 + 4));
      WO2f[ks] = pack8(*reinterpret_cast<const float4*>(q2 + ks * 32),
                       *reinterpret_cast<const float4*>(q2 + ks * 32 + 4));
    }
  }
  const float bo1v = bo1[c2 * 16 + l15];
  const float bo2v = bo2[c2 * 16 + l15];

  const int xr = tid >> 4;          // staging row 0..31
  const int xc = (tid & 15) * 4;    // staging col (4 floats)
  const float* Mb = Mg + (size_t)b * 256 * 64;

  float4 nv = *reinterpret_cast<const float4*>(Mb + xr * 64 + xc);  // chunk 0

  for (int ch = 0; ch < 8; ++ch) {
    // write staged chunk (cvt f32->bf16, swizzled)
    {
      unsigned p01 = ((unsigned)cvt1(nv.y) << 16) | cvt1(nv.x);
      unsigned p23 = ((unsigned)cvt1(nv.w) << 16) | cvt1(nv.z);
      int byte = (xr * 128 + xc * 2) ^ ((xr & 7) << 4);
      uint2 u = make_uint2(p01, p23);
      *reinterpret_cast<uint2*>(reinterpret_cast<char*>(sX) + byte) = u;
    }
    __syncthreads();   // X ready
    if (ch < 7)        // prefetch next chunk; latency hides under P1/P2
      nv = *reinterpret_cast<const float4*>(Mb + ((ch + 1) * 32 + xr) * 64 + xc);

    // P1 = relu(X @ WO1^T + bo1)
    {
      f32x4 acc = {0, 0, 0, 0};
      int arow = r2 * 16 + l15;
      #pragma unroll
      for (int ks = 0; ks < 2; ++ks)
        acc = __builtin_amdgcn_mfma_f32_16x16x32_bf16(
            ldfrag(sX, arow, ks * 64 + kb0, 128), WO1f[ks], acc, 0, 0, 0);
      #pragma unroll
      for (int r = 0; r < 4; ++r)
        st2(sP, r2 * 16 + lk * 4 + r, (c2 * 16 + l15) * 2, 128, cvt1(fmaxf(acc[r] + bo1v, 0.f)));
    }
    __syncthreads();   // P ready
    // P2 + rowsum accumulate
    {
      f32x4 acc = {0, 0, 0, 0};
      int arow = r2 * 16 + l15;
      #pragma unroll
      for (int ks = 0; ks < 2; ++ks)
        acc = __builtin_amdgcn_mfma_f32_16x16x32_bf16(
            ldfrag(sP, arow, ks * 64 + kb0, 128), WO2f[ks], acc, 0, 0, 0);
      float s = 0.f;
      #pragma unroll
      for (int r = 0; r < 4; ++r) s += fmaxf(acc[r] + bo2v, 0.f);
      s += __shfl_xor(s, 16);
      s += __shfl_xor(s, 32);
      if (lk == 0) sAccW[w][c2 * 16 + l15] += s;
    }
    __syncthreads();   // sX safe to overwrite (P1 done), sAccW settled
  }

  if (tid < 64) {
    float s = 0.f;
    #pragma unroll
    for (int ww = 0; ww < 8; ++ww) s += sAccW[ww][tid];
    sMean[tid] = s * (1.0f / 256.0f);
  }
  __syncthreads();
  if (tid < 128) {
    int c = tid >> 6;
    float v = sMean[l] * wo3[c * 64 + l];
    #pragma unroll
    for (int off = 32; off > 0; off >>= 1) v += __shfl_down(v, off);
    if (l == 0) out[b * 2 + c] = v + bo3[c];
  }
}

extern "C" void kernel_launch(void* const* d_in, const int* in_sizes, int n_in,
                              void* d_out, int out_size, void* d_ws, size_t ws_size,
                              hipStream_t stream) {
  (void)in_sizes; (void)n_in; (void)ws_size; (void)out_size;
  const float* se  = (const float*)d_in[1];   // d_in[0] = `inputs` — shape-only, never read
  const float* w1  = (const float*)d_in[2];
  const float* b1  = (const float*)d_in[3];
  const float* w2  = (const float*)d_in[4];
  const float* b2  = (const float*)d_in[5];
  const float* wo1 = (const float*)d_in[6];
  const float* bo1 = (const float*)d_in[7];
  const float* wo2 = (const float*)d_in[8];
  const float* bo2 = (const float*)d_in[9];
  const float* wo3 = (const float*)d_in[10];
  const float* bo3 = (const float*)d_in[11];

  float* Mg = (float*)d_ws;   // 256*256*64 f32 = 16.78 MB (harness ws proven >= 100 MB in r7)
  stage1_kernel<<<dim3(4096), dim3(512), 0, stream>>>(se, w1, b1, w2, b2, Mg);
  head_kernel<<<dim3(256), dim3(512), 0, stream>>>(Mg, wo1, bo1, wo2, bo2, wo3, bo3, (float*)d_out);
}